// Round 1
// baseline (605.848 us; speedup 1.0000x reference)
//
#include <hip/hip_runtime.h>
#include <hip/hip_bf16.h>
#include <cstdint>

typedef __attribute__((ext_vector_type(8))) short short8;
typedef __attribute__((ext_vector_type(4))) float f32x4;
typedef unsigned short ushort_t;
typedef unsigned int uint32;

#define DEVI static __device__ __forceinline__

DEVI ushort_t f2bf(float f){
  uint32 u = __builtin_bit_cast(uint32, f);
  u += 0x7FFFu + ((u >> 16) & 1u);
  return (ushort_t)(u >> 16);
}
DEVI float bf2f(ushort_t s){
  uint32 u = ((uint32)s) << 16;
  return __builtin_bit_cast(float, u);
}

typedef __attribute__((address_space(1))) const uint32 g_u32;
typedef __attribute__((address_space(3))) uint32 l_u32;
#define GL_LDS16(gp, lp) __builtin_amdgcn_global_load_lds((g_u32*)(gp), (l_u32*)(lp), 16, 0, 0)

// ---------------- fp32 -> bf16 conversion (x and the 4 weights) ----------------
__global__ __launch_bounds__(256) void convert_all(
    const float* __restrict__ x, const float* __restrict__ wq, const float* __restrict__ wk,
    const float* __restrict__ wv, const float* __restrict__ wo,
    ushort_t* __restrict__ xb, ushort_t* __restrict__ wqb, ushort_t* __restrict__ wkb,
    ushort_t* __restrict__ wvb, ushort_t* __restrict__ wob){
  int bid = blockIdx.x;
  const float* src; ushort_t* dst; long base;
  if (bid < 4096){ src = x; dst = xb; base = (long)bid * 2048; }
  else {
    int r = bid - 4096; int sel = r >> 9; int o = r & 511;
    src = sel==0?wq: sel==1?wk: sel==2?wv: wo;
    dst = sel==0?wqb: sel==1?wkb: sel==2?wvb: wob;
    base = (long)o * 2048;
  }
  long i = base + (long)threadIdx.x * 8;
  const float* p = src + i;
  float4 a = *(const float4*)p;
  float4 b = *(const float4*)(p + 4);
  short8 v;
  v[0]=(short)f2bf(a.x); v[1]=(short)f2bf(a.y); v[2]=(short)f2bf(a.z); v[3]=(short)f2bf(a.w);
  v[4]=(short)f2bf(b.x); v[5]=(short)f2bf(b.y); v[6]=(short)f2bf(b.z); v[7]=(short)f2bf(b.w);
  *(short8*)(dst + i) = v;
}

// ---------------- GEMM: C[M,N] = A[M,K] @ B[N,K]^T + bias ----------------
// MODE 0: write fp32 [M,N] to Cout
// MODE 1: write bf16 [b,h,t,d] layout (b=row>>11, tok=row&2047, h=col>>6, d=col&63)
template<int MODE>
__global__ __launch_bounds__(256) void gemm_bt(
    const ushort_t* __restrict__ A, const ushort_t* __restrict__ Bw,
    const float* __restrict__ bias, void* __restrict__ Cout,
    int Ndim, int Kdim){
  __shared__ ushort_t As[4096];
  __shared__ ushort_t Bs[4096];
  const int tid = threadIdx.x, l = tid & 63, w = tid >> 6;
  const int lr = l & 15, lg = l >> 4;
  const int nb = Ndim >> 7;
  const int bm = blockIdx.x / nb, bn = blockIdx.x % nb;
  const int m0 = bm << 7, n0 = bn << 7;
  const int wm = (w >> 1) << 6, wn = (w & 1) << 6;
  f32x4 acc[4][4] = {};
  const ushort_t* aS = A + (long)(m0 + (tid >> 2)) * Kdim + (tid & 3) * 8;
  const ushort_t* bS = Bw + (long)(n0 + (tid >> 2)) * Kdim + (tid & 3) * 8;
  const long skip = (long)64 * Kdim;
  const int nk = Kdim >> 5;
  for (int kt = 0; kt < nk; ++kt){
    GL_LDS16(aS,        &As[w * 512]);
    GL_LDS16(aS + skip, &As[2048 + w * 512]);
    GL_LDS16(bS,        &Bs[w * 512]);
    GL_LDS16(bS + skip, &Bs[2048 + w * 512]);
    aS += 32; bS += 32;
    __syncthreads();
    short8 af[4], bfr[4];
#pragma unroll
    for (int mi = 0; mi < 4; ++mi) af[mi]  = *(const short8*)&As[(wm + mi*16 + lr)*32 + lg*8];
#pragma unroll
    for (int ni = 0; ni < 4; ++ni) bfr[ni] = *(const short8*)&Bs[(wn + ni*16 + lr)*32 + lg*8];
#pragma unroll
    for (int mi = 0; mi < 4; ++mi)
#pragma unroll
      for (int ni = 0; ni < 4; ++ni)
        acc[mi][ni] = __builtin_amdgcn_mfma_f32_16x16x32_bf16(af[mi], bfr[ni], acc[mi][ni], 0, 0, 0);
    __syncthreads();
  }
  const int colBase = n0 + wn + lr;
#pragma unroll
  for (int mi = 0; mi < 4; ++mi){
    const int row0 = m0 + wm + mi*16 + lg*4;
#pragma unroll
    for (int ni = 0; ni < 4; ++ni){
      const int col = colBase + ni*16;
      const float bv = bias[col];
#pragma unroll
      for (int i = 0; i < 4; ++i){
        float v = acc[mi][ni][i] + bv;
        if (MODE == 0){
          ((float*)Cout)[(long)(row0 + i) * Ndim + col] = v;
        } else {
          const int r = row0 + i;
          const int b = r >> 11, tok = r & 2047;
          const int h = col >> 6, d = col & 63;
          ((ushort_t*)Cout)[(((long)(b*16 + h) * 2048 + tok) << 6) + d] = f2bf(v);
        }
      }
    }
  }
}

// ---------------- RoPE in-place on Q,K (bf16 [bh, t, 64]) ----------------
__global__ __launch_bounds__(256) void rope_qk(ushort_t* __restrict__ Qb, ushort_t* __restrict__ Kb){
  const long idx = (long)blockIdx.x * 256 + threadIdx.x;   // 64*2048*32 total
  const int j = (int)(idx & 31);
  const int tok = (int)((idx >> 5) & 2047);
  const float theta = exp2f(-(float)j * 0.4152410118609203f);   // log2(10000)/32
  const float ang = (float)(tok + 1) * theta;
  float s, c;
  sincosf(ang, &s, &c);
  const long base = ((idx >> 5) << 6) + j;
  float q0 = bf2f(Qb[base]), q1 = bf2f(Qb[base + 32]);
  Qb[base]      = f2bf(q0 * c - q1 * s);
  Qb[base + 32] = f2bf(q1 * c + q0 * s);
  float k0 = bf2f(Kb[base]), k1 = bf2f(Kb[base + 32]);
  Kb[base]      = f2bf(k0 * c - k1 * s);
  Kb[base + 32] = f2bf(k1 * c + k0 * s);
}

// ---------------- V transpose: [bh, t, d] -> [bh, d, t] ----------------
__global__ __launch_bounds__(256) void vtrans(const ushort_t* __restrict__ Vb, ushort_t* __restrict__ Vt){
  __shared__ ushort_t tile[64][72];
  const int tid = threadIdx.x;
  const int bh = blockIdx.x >> 5, t0 = (blockIdx.x & 31) << 6;
  const ushort_t* src = Vb + ((long)bh * 2048 + t0) * 64;
#pragma unroll
  for (int it = 0; it < 2; ++it){
    int e = it * 2048 + tid * 8;
    int tr = e >> 6, tc = e & 63;
    *(short8*)&tile[tr][tc] = *(const short8*)&src[e];
  }
  __syncthreads();
  ushort_t* dst = Vt + (long)bh * 64 * 2048 + t0;
#pragma unroll
  for (int it = 0; it < 2; ++it){
    int e = it * 2048 + tid * 8;
    int d = e >> 6, tc = e & 63;
    short8 v;
#pragma unroll
    for (int ii = 0; ii < 8; ++ii) v[ii] = (short)tile[tc + ii][d];
    *(short8*)&dst[(long)d * 2048 + tc] = v;
  }
}

// ---------------- flash attention (causal) ----------------
// grid: bh(64) x qchunk(32); 4 waves/block, each wave owns 16 q rows.
__global__ __launch_bounds__(256) void attn(
    const ushort_t* __restrict__ Qb, const ushort_t* __restrict__ Kb,
    const ushort_t* __restrict__ Vt, ushort_t* __restrict__ yb){
  __shared__ ushort_t Plds[4][1152];   // per-wave 16 x 72 (padded) bf16 P tile
  const int tid = threadIdx.x, l = tid & 63, w = tid >> 6;
  const int lr = l & 15, lg = l >> 4;
  const int bh = blockIdx.x >> 5, qc = blockIdx.x & 31;
  const int q0 = qc * 64 + w * 16;
  const ushort_t* Qh = Qb + (long)bh * 2048 * 64;
  const ushort_t* Kh = Kb + (long)bh * 2048 * 64;
  const ushort_t* Vh = Vt + (long)bh * 64 * 2048;
  short8 aq0 = *(const short8*)&Qh[(q0 + lr) * 64 + lg * 8];
  short8 aq1 = *(const short8*)&Qh[(q0 + lr) * 64 + 32 + lg * 8];
  f32x4 o[4] = {};
  float mrun[4], lsum[4];
#pragma unroll
  for (int i = 0; i < 4; ++i){ mrun[i] = -__builtin_inff(); lsum[i] = 0.f; }
  const int ktEnd = (q0 + 15) >> 6;
  const float cl2 = 0.1803368801111204f;   // log2(e)/8
  ushort_t* P = Plds[w];
  for (int kt = 0; kt <= ktEnd; ++kt){
    const int k0 = kt << 6;
    f32x4 s[4];
#pragma unroll
    for (int kc = 0; kc < 4; ++kc){
      const ushort_t* kp = &Kh[(k0 + kc*16 + lr) * 64 + lg * 8];
      short8 b0 = *(const short8*)kp;
      short8 b1 = *(const short8*)(kp + 32);
      f32x4 z = {0.f, 0.f, 0.f, 0.f};
      z = __builtin_amdgcn_mfma_f32_16x16x32_bf16(aq0, b0, z, 0, 0, 0);
      s[kc] = __builtin_amdgcn_mfma_f32_16x16x32_bf16(aq1, b1, z, 0, 0, 0);
    }
    if (kt == ktEnd){
#pragma unroll
      for (int kc = 0; kc < 4; ++kc){
        const int col = k0 + kc*16 + lr;
#pragma unroll
        for (int i = 0; i < 4; ++i){
          if (col > q0 + lg*4 + i) s[kc][i] = -__builtin_inff();
        }
      }
    }
    float mx[4];
#pragma unroll
    for (int i = 0; i < 4; ++i) mx[i] = fmaxf(fmaxf(s[0][i], s[1][i]), fmaxf(s[2][i], s[3][i]));
#pragma unroll
    for (int d = 1; d < 16; d <<= 1)
#pragma unroll
      for (int i = 0; i < 4; ++i) mx[i] = fmaxf(mx[i], __shfl_xor(mx[i], d));
    float al[4], rs[4];
#pragma unroll
    for (int i = 0; i < 4; ++i){
      float mn = fmaxf(mrun[i], mx[i]);
      al[i] = exp2f((mrun[i] - mn) * cl2);
      mrun[i] = mn;
      rs[i] = 0.f;
    }
#pragma unroll
    for (int kc = 0; kc < 4; ++kc)
#pragma unroll
      for (int i = 0; i < 4; ++i){
        float p = exp2f((s[kc][i] - mrun[i]) * cl2);
        s[kc][i] = p;
        rs[i] += p;
      }
#pragma unroll
    for (int d = 1; d < 16; d <<= 1)
#pragma unroll
      for (int i = 0; i < 4; ++i) rs[i] += __shfl_xor(rs[i], d);
#pragma unroll
    for (int i = 0; i < 4; ++i) lsum[i] = lsum[i] * al[i] + rs[i];
#pragma unroll
    for (int n = 0; n < 4; ++n)
#pragma unroll
      for (int i = 0; i < 4; ++i) o[n][i] *= al[i];
#pragma unroll
    for (int kc = 0; kc < 4; ++kc)
#pragma unroll
      for (int i = 0; i < 4; ++i)
        P[(lg*4 + i) * 72 + kc*16 + lr] = f2bf(s[kc][i]);
    short8 pa0 = *(const short8*)&P[lr * 72 + lg * 8];
    short8 pa1 = *(const short8*)&P[lr * 72 + 32 + lg * 8];
#pragma unroll
    for (int n = 0; n < 4; ++n){
      const ushort_t* vp = &Vh[(n*16 + lr) * 2048 + k0 + lg * 8];
      short8 v0 = *(const short8*)vp;
      short8 v1 = *(const short8*)(vp + 32);
      o[n] = __builtin_amdgcn_mfma_f32_16x16x32_bf16(pa0, v0, o[n], 0, 0, 0);
      o[n] = __builtin_amdgcn_mfma_f32_16x16x32_bf16(pa1, v1, o[n], 0, 0, 0);
    }
  }
  const int b = bh >> 4, h = bh & 15;
#pragma unroll
  for (int n = 0; n < 4; ++n)
#pragma unroll
    for (int i = 0; i < 4; ++i){
      const int tok = q0 + lg*4 + i;
      yb[((long)(b * 2048 + tok)) * 1024 + h*64 + n*16 + lr] = f2bf(o[n][i] / lsum[i]);
    }
}

// ---------------- launch ----------------
extern "C" void kernel_launch(void* const* d_in, const int* in_sizes, int n_in,
                              void* d_out, int out_size, void* d_ws, size_t ws_size,
                              hipStream_t stream){
  const float* x  = (const float*)d_in[0];
  const float* Wq = (const float*)d_in[1];
  const float* bq = (const float*)d_in[2];
  const float* Wk = (const float*)d_in[3];
  const float* bk = (const float*)d_in[4];
  const float* Wv = (const float*)d_in[5];
  const float* bv = (const float*)d_in[6];
  const float* Wo = (const float*)d_in[7];
  const float* bo = (const float*)d_in[8];
  char* ws = (char*)d_ws;
  ushort_t* xb  = (ushort_t*)(ws);                    // 16 MB, reused as yb after attn
  ushort_t* wqb = (ushort_t*)(ws + 16777216);
  ushort_t* wkb = (ushort_t*)(ws + 18874368);
  ushort_t* wvb = (ushort_t*)(ws + 20971520);
  ushort_t* wob = (ushort_t*)(ws + 23068672);
  ushort_t* Qb  = (ushort_t*)(ws + 25165824);
  ushort_t* Kb  = (ushort_t*)(ws + 41943040);
  ushort_t* Vb  = (ushort_t*)(ws + 58720256);
  ushort_t* Vt  = (ushort_t*)(ws + 75497472);
  ushort_t* yb  = xb;

  convert_all<<<6144, 256, 0, stream>>>(x, Wq, Wk, Wv, Wo, xb, wqb, wkb, wvb, wob);
  gemm_bt<1><<<512, 256, 0, stream>>>(xb, wqb, bq, (void*)Qb, 1024, 1024);
  gemm_bt<1><<<512, 256, 0, stream>>>(xb, wkb, bk, (void*)Kb, 1024, 1024);
  gemm_bt<1><<<512, 256, 0, stream>>>(xb, wvb, bv, (void*)Vb, 1024, 1024);
  rope_qk<<<16384, 256, 0, stream>>>(Qb, Kb);
  vtrans<<<2048, 256, 0, stream>>>(Vb, Vt);
  attn<<<2048, 256, 0, stream>>>(Qb, Kb, Vt, yb);
  gemm_bt<0><<<512, 256, 0, stream>>>(yb, wob, bo, d_out, 1024, 1024);
}

// Round 2
// 288.680 us; speedup vs baseline: 2.0987x; 2.0987x over previous
//
#include <hip/hip_runtime.h>
#include <hip/hip_bf16.h>
#include <cstdint>

typedef __attribute__((ext_vector_type(8))) short short8;
typedef __attribute__((ext_vector_type(4))) short short4v;
typedef __attribute__((ext_vector_type(4))) float f32x4;
typedef __attribute__((ext_vector_type(16))) float f32x16;
typedef __attribute__((ext_vector_type(4))) unsigned int u32x4;
typedef unsigned short ushort_t;
typedef unsigned int uint32;

#define DEVI static __device__ __forceinline__

DEVI ushort_t f2bf(float f){
  uint32 u = __builtin_bit_cast(uint32, f);
  u += 0x7FFFu + ((u >> 16) & 1u);
  return (ushort_t)(u >> 16);
}
DEVI float bf2f(ushort_t s){
  uint32 u = ((uint32)s) << 16;
  return __builtin_bit_cast(float, u);
}
DEVI uint32 cvtpk_bf16(float lo, float hi){
  uint32 r;
  asm("v_cvt_pk_bf16_f32 %0, %1, %2" : "=v"(r) : "v"(lo), "v"(hi));
  return r;
}
DEVI void plswap(uint32& a, uint32& b){
  asm("v_permlane32_swap_b32 %0, %1" : "+v"(a), "+v"(b));
}

typedef __attribute__((address_space(1))) const uint32 g_u32;
typedef __attribute__((address_space(3))) uint32 l_u32;
#define GL_LDS16(gp, lp) __builtin_amdgcn_global_load_lds((g_u32*)(gp), (l_u32*)(lp), 16, 0, 0)

// ---------------- fp32 -> bf16 conversion (x and the 4 weights) ----------------
__global__ __launch_bounds__(256) void convert_all(
    const float* __restrict__ x, const float* __restrict__ wq, const float* __restrict__ wk,
    const float* __restrict__ wv, const float* __restrict__ wo,
    ushort_t* __restrict__ xb, ushort_t* __restrict__ wqb, ushort_t* __restrict__ wkb,
    ushort_t* __restrict__ wvb, ushort_t* __restrict__ wob){
  int bid = blockIdx.x;
  const float* src; ushort_t* dst; long base;
  if (bid < 4096){ src = x; dst = xb; base = (long)bid * 2048; }
  else {
    int r = bid - 4096; int sel = r >> 9; int o = r & 511;
    src = sel==0?wq: sel==1?wk: sel==2?wv: wo;
    dst = sel==0?wqb: sel==1?wkb: sel==2?wvb: wob;
    base = (long)o * 2048;
  }
  long i = base + (long)threadIdx.x * 8;
  const float* p = src + i;
  float4 a = *(const float4*)p;
  float4 b = *(const float4*)(p + 4);
  short8 v;
  v[0]=(short)f2bf(a.x); v[1]=(short)f2bf(a.y); v[2]=(short)f2bf(a.z); v[3]=(short)f2bf(a.w);
  v[4]=(short)f2bf(b.x); v[5]=(short)f2bf(b.y); v[6]=(short)f2bf(b.z); v[7]=(short)f2bf(b.w);
  *(short8*)(dst + i) = v;
}

// ---------------- GEMM: C[M,N] = A[M,K] @ B[N,K]^T + bias ----------------
template<int MODE>
__global__ __launch_bounds__(256) void gemm_bt(
    const ushort_t* __restrict__ A, const ushort_t* __restrict__ Bw,
    const float* __restrict__ bias, void* __restrict__ Cout,
    int Ndim, int Kdim){
  __shared__ ushort_t As[4096];
  __shared__ ushort_t Bs[4096];
  const int tid = threadIdx.x, l = tid & 63, w = tid >> 6;
  const int lr = l & 15, lg = l >> 4;
  const int nb = Ndim >> 7;
  const int bm = blockIdx.x / nb, bn = blockIdx.x % nb;
  const int m0 = bm << 7, n0 = bn << 7;
  const int wm = (w >> 1) << 6, wn = (w & 1) << 6;
  f32x4 acc[4][4] = {};
  const ushort_t* aS = A + (long)(m0 + (tid >> 2)) * Kdim + (tid & 3) * 8;
  const ushort_t* bS = Bw + (long)(n0 + (tid >> 2)) * Kdim + (tid & 3) * 8;
  const long skip = (long)64 * Kdim;
  const int nk = Kdim >> 5;
  for (int kt = 0; kt < nk; ++kt){
    GL_LDS16(aS,        &As[w * 512]);
    GL_LDS16(aS + skip, &As[2048 + w * 512]);
    GL_LDS16(bS,        &Bs[w * 512]);
    GL_LDS16(bS + skip, &Bs[2048 + w * 512]);
    aS += 32; bS += 32;
    __syncthreads();
    short8 af[4], bfr[4];
#pragma unroll
    for (int mi = 0; mi < 4; ++mi) af[mi]  = *(const short8*)&As[(wm + mi*16 + lr)*32 + lg*8];
#pragma unroll
    for (int ni = 0; ni < 4; ++ni) bfr[ni] = *(const short8*)&Bs[(wn + ni*16 + lr)*32 + lg*8];
#pragma unroll
    for (int mi = 0; mi < 4; ++mi)
#pragma unroll
      for (int ni = 0; ni < 4; ++ni)
        acc[mi][ni] = __builtin_amdgcn_mfma_f32_16x16x32_bf16(af[mi], bfr[ni], acc[mi][ni], 0, 0, 0);
    __syncthreads();
  }
  const int colBase = n0 + wn + lr;
#pragma unroll
  for (int mi = 0; mi < 4; ++mi){
    const int row0 = m0 + wm + mi*16 + lg*4;
#pragma unroll
    for (int ni = 0; ni < 4; ++ni){
      const int col = colBase + ni*16;
      const float bv = bias[col];
#pragma unroll
      for (int i = 0; i < 4; ++i){
        float v = acc[mi][ni][i] + bv;
        if (MODE == 0){
          ((float*)Cout)[(long)(row0 + i) * Ndim + col] = v;
        } else {
          const int r = row0 + i;
          const int b = r >> 11, tok = r & 2047;
          const int h = col >> 6, d = col & 63;
          ((ushort_t*)Cout)[(((long)(b*16 + h) * 2048 + tok) << 6) + d] = f2bf(v);
        }
      }
    }
  }
}

// ---------------- RoPE in-place on Q,K (bf16 [bh, t, 64]) ----------------
__global__ __launch_bounds__(256) void rope_qk(ushort_t* __restrict__ Qb, ushort_t* __restrict__ Kb){
  const long idx = (long)blockIdx.x * 256 + threadIdx.x;
  const int j = (int)(idx & 31);
  const int tok = (int)((idx >> 5) & 2047);
  const float theta = exp2f(-(float)j * 0.4152410118609203f);
  const float ang = (float)(tok + 1) * theta;
  float s, c;
  sincosf(ang, &s, &c);
  const long base = ((idx >> 5) << 6) + j;
  float q0 = bf2f(Qb[base]), q1 = bf2f(Qb[base + 32]);
  Qb[base]      = f2bf(q0 * c - q1 * s);
  Qb[base + 32] = f2bf(q1 * c + q0 * s);
  float k0 = bf2f(Kb[base]), k1 = bf2f(Kb[base + 32]);
  Kb[base]      = f2bf(k0 * c - k1 * s);
  Kb[base + 32] = f2bf(k1 * c + k0 * s);
}

// ---------------- V transpose: [bh, t, d] -> [bh, d, t] ----------------
__global__ __launch_bounds__(256) void vtrans(const ushort_t* __restrict__ Vb, ushort_t* __restrict__ Vt){
  __shared__ ushort_t tile[64][72];
  const int tid = threadIdx.x;
  const int bh = blockIdx.x >> 5, t0 = (blockIdx.x & 31) << 6;
  const ushort_t* src = Vb + ((long)bh * 2048 + t0) * 64;
#pragma unroll
  for (int it = 0; it < 2; ++it){
    int e = it * 2048 + tid * 8;
    int tr = e >> 6, tc = e & 63;
    *(short8*)&tile[tr][tc] = *(const short8*)&src[e];
  }
  __syncthreads();
  ushort_t* dst = Vt + (long)bh * 64 * 2048 + t0;
#pragma unroll
  for (int it = 0; it < 2; ++it){
    int e = it * 2048 + tid * 8;
    int d = e >> 6, tc = e & 63;
    short8 v;
#pragma unroll
    for (int ii = 0; ii < 8; ++ii) v[ii] = (short)tile[tc + ii][d];
    *(short8*)&dst[(long)d * 2048 + tc] = v;
  }
}

// ---------------- flash attention (causal), swapped-QK 32x32 ----------------
// one wave per 32 q rows; grid = 64 qchunks x 64 bh, heavy chunks first.
__global__ __launch_bounds__(64, 4) void attn(
    const ushort_t* __restrict__ Qb, const ushort_t* __restrict__ Kb,
    const ushort_t* __restrict__ Vt, ushort_t* __restrict__ yb){
  const int l = threadIdx.x;
  const int lq = l & 31;          // q column within tile
  const int hi = l >> 5;          // 0 = low half, 1 = high half
  const int widx = blockIdx.x;
  const int bh = widx & 63;
  const int qc = 63 - (widx >> 6);   // heavy (large q0) first
  const int q0 = qc << 5;
  const ushort_t* Qh = Qb + (long)bh * 2048 * 64;
  const ushort_t* Kh = Kb + (long)bh * 2048 * 64;
  const ushort_t* Vh = Vt + (long)bh * 64 * 2048;
  const int h8 = hi * 8;
  // Q as B-operand fragments: lane holds Q[q0+lq][c*16 + hi*8 + j]
  const ushort_t* qp = &Qh[(long)(q0 + lq) * 64 + h8];
  short8 qf0 = *(const short8*)(qp);
  short8 qf1 = *(const short8*)(qp + 16);
  short8 qf2 = *(const short8*)(qp + 32);
  short8 qf3 = *(const short8*)(qp + 48);
  f32x16 o0 = {}, o1 = {};
  float m = -__builtin_inff(), lsum = 0.f;
  const float cl2 = 0.1803368801111204f;   // log2(e)/8  (folds the 1/sqrt(64) scale)
  for (int kt = 0; kt <= qc; ++kt){
    const int k0 = kt << 5;
    // K A-operand fragments: lane holds K[k0+lq][c*16 + hi*8 + j]
    const ushort_t* kp = &Kh[(long)(k0 + lq) * 64 + h8];
    short8 kf0 = *(const short8*)(kp);
    short8 kf1 = *(const short8*)(kp + 16);
    short8 kf2 = *(const short8*)(kp + 32);
    short8 kf3 = *(const short8*)(kp + 48);
    // V^T A-operand fragments (issued early; consumed after softmax)
    const ushort_t* vp = &Vh[(long)lq * 2048 + k0 + h8];
    short8 vf00 = *(const short8*)(vp);
    short8 vf01 = *(const short8*)(vp + 16);
    short8 vf10 = *(const short8*)(vp + 32 * 2048);
    short8 vf11 = *(const short8*)(vp + 32 * 2048 + 16);
    // S^T[k][q] = sum_d K[k][d] Q[q][d]
    f32x16 s = {};
    s = __builtin_amdgcn_mfma_f32_32x32x16_bf16(kf0, qf0, s, 0, 0, 0);
    s = __builtin_amdgcn_mfma_f32_32x32x16_bf16(kf1, qf1, s, 0, 0, 0);
    s = __builtin_amdgcn_mfma_f32_32x32x16_bf16(kf2, qf2, s, 0, 0, 0);
    s = __builtin_amdgcn_mfma_f32_32x32x16_bf16(kf3, qf3, s, 0, 0, 0);
    if (kt == qc){
      // diagonal tile: mask k > q  (k = k0 + rk, q = q0 + lq, k0 == q0)
#pragma unroll
      for (int r = 0; r < 16; ++r){
        const int rk = (r & 3) + 8 * (r >> 2) + 4 * hi;
        if (rk > lq) s[r] = -__builtin_inff();
      }
    }
    // online softmax for q = lq (lane pair l, l^32 hold the 32 k values)
    float pm = s[0];
#pragma unroll
    for (int r = 1; r < 16; ++r) pm = fmaxf(pm, s[r]);
    pm = fmaxf(pm, __shfl_xor(pm, 32));
    const float mn = fmaxf(m, pm);
    const float al = exp2f((m - mn) * cl2);
    m = mn;
    float rs = 0.f;
#pragma unroll
    for (int r = 0; r < 16; ++r){
      const float p = exp2f((s[r] - m) * cl2);
      s[r] = p;
      rs += p;
    }
    rs += __shfl_xor(rs, 32);
    lsum = lsum * al + rs;
#pragma unroll
    for (int r = 0; r < 16; ++r){ o0[r] *= al; o1[r] *= al; }
    // P^T -> bf16 B-operand fragments via cvt_pk + permlane32_swap
    uint32 a0 = cvtpk_bf16(s[0], s[1]),  b0 = cvtpk_bf16(s[4], s[5]);
    uint32 a1 = cvtpk_bf16(s[2], s[3]),  b1 = cvtpk_bf16(s[6], s[7]);
    uint32 a2 = cvtpk_bf16(s[8], s[9]),  b2 = cvtpk_bf16(s[12], s[13]);
    uint32 a3 = cvtpk_bf16(s[10], s[11]),b3 = cvtpk_bf16(s[14], s[15]);
    plswap(a0, b0);   // a0 = chunk0 reg0, b0 = chunk0 reg2
    plswap(a1, b1);   // a1 = chunk0 reg1, b1 = chunk0 reg3
    plswap(a2, b2);   // a2 = chunk1 reg0, b2 = chunk1 reg2
    plswap(a3, b3);   // a3 = chunk1 reg1, b3 = chunk1 reg3
    u32x4 pc0 = {a0, a1, b0, b1};
    u32x4 pc1 = {a2, a3, b2, b3};
    short8 pb0 = __builtin_bit_cast(short8, pc0);
    short8 pb1 = __builtin_bit_cast(short8, pc1);
    // O^T[d][q] += V^T[d][k] P^T[k][q]
    o0 = __builtin_amdgcn_mfma_f32_32x32x16_bf16(vf00, pb0, o0, 0, 0, 0);
    o0 = __builtin_amdgcn_mfma_f32_32x32x16_bf16(vf01, pb1, o0, 0, 0, 0);
    o1 = __builtin_amdgcn_mfma_f32_32x32x16_bf16(vf10, pb0, o1, 0, 0, 0);
    o1 = __builtin_amdgcn_mfma_f32_32x32x16_bf16(vf11, pb1, o1, 0, 0, 0);
  }
  const float inv = 1.0f / lsum;
  const int b = bh >> 4, h = bh & 15;
  const int tok = q0 + lq;
  ushort_t* yrow = yb + (long)(b * 2048 + tok) * 1024 + h * 64;
#pragma unroll
  for (int g = 0; g < 4; ++g){
    short4v p0, p1;
#pragma unroll
    for (int j = 0; j < 4; ++j){
      p0[j] = (short)f2bf(o0[4*g + j] * inv);
      p1[j] = (short)f2bf(o1[4*g + j] * inv);
    }
    *(short4v*)&yrow[8*g + 4*hi]      = p0;
    *(short4v*)&yrow[32 + 8*g + 4*hi] = p1;
  }
}

// ---------------- launch ----------------
extern "C" void kernel_launch(void* const* d_in, const int* in_sizes, int n_in,
                              void* d_out, int out_size, void* d_ws, size_t ws_size,
                              hipStream_t stream){
  const float* x  = (const float*)d_in[0];
  const float* Wq = (const float*)d_in[1];
  const float* bq = (const float*)d_in[2];
  const float* Wk = (const float*)d_in[3];
  const float* bk = (const float*)d_in[4];
  const float* Wv = (const float*)d_in[5];
  const float* bv = (const float*)d_in[6];
  const float* Wo = (const float*)d_in[7];
  const float* bo = (const float*)d_in[8];
  char* ws = (char*)d_ws;
  ushort_t* xb  = (ushort_t*)(ws);                    // 16 MB, reused as yb after attn
  ushort_t* wqb = (ushort_t*)(ws + 16777216);
  ushort_t* wkb = (ushort_t*)(ws + 18874368);
  ushort_t* wvb = (ushort_t*)(ws + 20971520);
  ushort_t* wob = (ushort_t*)(ws + 23068672);
  ushort_t* Qb  = (ushort_t*)(ws + 25165824);
  ushort_t* Kb  = (ushort_t*)(ws + 41943040);
  ushort_t* Vb  = (ushort_t*)(ws + 58720256);
  ushort_t* Vt  = (ushort_t*)(ws + 75497472);
  ushort_t* yb  = xb;

  convert_all<<<6144, 256, 0, stream>>>(x, Wq, Wk, Wv, Wo, xb, wqb, wkb, wvb, wob);
  gemm_bt<1><<<512, 256, 0, stream>>>(xb, wqb, bq, (void*)Qb, 1024, 1024);
  gemm_bt<1><<<512, 256, 0, stream>>>(xb, wkb, bk, (void*)Kb, 1024, 1024);
  gemm_bt<1><<<512, 256, 0, stream>>>(xb, wvb, bv, (void*)Vb, 1024, 1024);
  rope_qk<<<16384, 256, 0, stream>>>(Qb, Kb);
  vtrans<<<2048, 256, 0, stream>>>(Vb, Vt);
  attn<<<4096, 64, 0, stream>>>(Qb, Kb, Vt, yb);
  gemm_bt<0><<<512, 256, 0, stream>>>(yb, wob, bo, d_out, 1024, 1024);
}